// Round 1
// baseline (77.508 us; speedup 1.0000x reference)
//
#include <hip/hip_runtime.h>
#include <math.h>

// ArcFace fused loss, B=512, C=100000, float32.
// loss_b = logsumexp_c(64*arcrow) - 64*theta_valid ; out = mean_b loss_b
// logsumexp computed with fixed shift 64 (inputs bounded by |x|<1 -> 64x<64).

#define BB 512
#define CC 100000
#define C4 (CC / 4)
#define BLK 1024

__device__ __forceinline__ float wave_reduce_add(float v) {
    #pragma unroll
    for (int off = 32; off > 0; off >>= 1)
        v += __shfl_down(v, off, 64);
    return v;
}

__global__ __launch_bounds__(BLK) void arcface_rows(const float* __restrict__ y_true,
                                                    const float* __restrict__ logits,
                                                    float* __restrict__ row_loss) {
    const int row = blockIdx.x;
    const int tid = threadIdx.x;
    const float4* __restrict__ y4 = (const float4*)(y_true + (size_t)row * CC);
    const float4* __restrict__ x4 = (const float4*)(logits + (size_t)row * CC);

    __shared__ float s_val;           // logit at the one-hot label position
    __shared__ float s_wave[BLK / 64];

    float s = 0.0f;

    for (int i = tid; i < C4; i += BLK) {
        const float4 y = y4[i];
        const float4 x = x4[i];
        s += __expf(64.0f * x.x - 64.0f);
        s += __expf(64.0f * x.y - 64.0f);
        s += __expf(64.0f * x.z - 64.0f);
        s += __expf(64.0f * x.w - 64.0f);
        // one-hot: exactly one element in the row is 1.0 — single writer, no race
        if (y.x > 0.5f) s_val = x.x;
        if (y.y > 0.5f) s_val = x.y;
        if (y.z > 0.5f) s_val = x.z;
        if (y.w > 0.5f) s_val = x.w;
    }

    // block reduction of s
    s = wave_reduce_add(s);
    const int wid = tid >> 6;
    if ((tid & 63) == 0) s_wave[wid] = s;
    __syncthreads();

    if (tid == 0) {
        float total = 0.0f;
        #pragma unroll
        for (int w = 0; w < BLK / 64; ++w) total += s_wave[w];

        const float v = s_val;
        // margin1=1, margin2=0.5, margin3=0
        const float THRESH = -0.8775825618903728f;  // cos(pi - 0.5)
        const float theta = cosf(acosf(v) + 0.5f);
        const float tv = (v > THRESH) ? theta : (-2.0f - theta);

        // swap label term: remove exp(64v-64), add exp(64*tv-64)
        total += __expf(64.0f * tv - 64.0f) - __expf(64.0f * v - 64.0f);

        // loss_b = (64 + log(total)) - 64*tv
        row_loss[row] = 64.0f + logf(total) - 64.0f * tv;
    }
}

__global__ __launch_bounds__(BB) void reduce_rows(const float* __restrict__ row_loss,
                                                  float* __restrict__ out) {
    const int tid = threadIdx.x;  // 512 threads
    float v = row_loss[tid];
    v = wave_reduce_add(v);
    __shared__ float s_wave[BB / 64];
    if ((tid & 63) == 0) s_wave[tid >> 6] = v;
    __syncthreads();
    if (tid == 0) {
        float t = 0.0f;
        #pragma unroll
        for (int w = 0; w < BB / 64; ++w) t += s_wave[w];
        out[0] = t * (1.0f / (float)BB);
    }
}

extern "C" void kernel_launch(void* const* d_in, const int* in_sizes, int n_in,
                              void* d_out, int out_size, void* d_ws, size_t ws_size,
                              hipStream_t stream) {
    const float* y_true = (const float*)d_in[0];
    const float* logits = (const float*)d_in[1];
    float* out = (float*)d_out;
    float* row_loss = (float*)d_ws;  // 512 floats

    arcface_rows<<<BB, BLK, 0, stream>>>(y_true, logits, row_loss);
    reduce_rows<<<1, BB, 0, stream>>>(row_loss, out);
}

// Round 2
// 75.458 us; speedup vs baseline: 1.0272x; 1.0272x over previous
//
#include <hip/hip_runtime.h>
#include <math.h>

// ArcFace fused loss, B=512, C=100000, float32.
// loss_b = logsumexp_c(64*arcrow) - 64*theta_valid ; out = mean_b loss_b
// Fixed-shift logsumexp (|x|<1 -> 64x-64 in (-128,0), no overflow; underflow harmless).

#define BB 512
#define CC 100000
#define C4 (CC / 4)           // 25000 float4 per row
#define BLK 1024
#define SWEEPS 6              // 6 * 4 * 1024 = 24576 float4
#define TAIL (C4 - SWEEPS * 4 * BLK)   // 424

__device__ __forceinline__ float wave_reduce_add(float v) {
    #pragma unroll
    for (int off = 32; off > 0; off >>= 1)
        v += __shfl_down(v, off, 64);
    return v;
}

__device__ __forceinline__ float e64(float x) {
    // exp(64x - 64)
    return __expf(fmaf(64.0f, x, -64.0f));
}

__global__ __launch_bounds__(BLK, 8) void arcface_rows(const float* __restrict__ y_true,
                                                       const float* __restrict__ logits,
                                                       float* __restrict__ row_loss) {
    const int row = blockIdx.x;
    const int tid = threadIdx.x;
    const float4* __restrict__ y4 = (const float4*)(y_true + (size_t)row * CC);
    const float4* __restrict__ x4 = (const float4*)(logits + (size_t)row * CC);

    __shared__ float s_val;           // logit at the one-hot label position
    __shared__ float s_wave[BLK / 64];

    float s = 0.0f;
    int i = tid;

    #pragma unroll 1
    for (int k = 0; k < SWEEPS; ++k, i += 4 * BLK) {
        // issue 8 loads up front for MLP
        const float4 ya = y4[i];
        const float4 yb = y4[i + BLK];
        const float4 yc = y4[i + 2 * BLK];
        const float4 yd = y4[i + 3 * BLK];
        const float4 xa = x4[i];
        const float4 xb = x4[i + BLK];
        const float4 xc = x4[i + 2 * BLK];
        const float4 xd = x4[i + 3 * BLK];

        s += e64(xa.x); s += e64(xa.y); s += e64(xa.z); s += e64(xa.w);
        s += e64(xb.x); s += e64(xb.y); s += e64(xb.z); s += e64(xb.w);
        s += e64(xc.x); s += e64(xc.y); s += e64(xc.z); s += e64(xc.w);
        s += e64(xd.x); s += e64(xd.y); s += e64(xd.z); s += e64(xd.w);

        // one-hot: exactly one element in the row is 1.0 — single writer, no race
        if (ya.x > 0.5f) s_val = xa.x;
        if (ya.y > 0.5f) s_val = xa.y;
        if (ya.z > 0.5f) s_val = xa.z;
        if (ya.w > 0.5f) s_val = xa.w;
        if (yb.x > 0.5f) s_val = xb.x;
        if (yb.y > 0.5f) s_val = xb.y;
        if (yb.z > 0.5f) s_val = xb.z;
        if (yb.w > 0.5f) s_val = xb.w;
        if (yc.x > 0.5f) s_val = xc.x;
        if (yc.y > 0.5f) s_val = xc.y;
        if (yc.z > 0.5f) s_val = xc.z;
        if (yc.w > 0.5f) s_val = xc.w;
        if (yd.x > 0.5f) s_val = xd.x;
        if (yd.y > 0.5f) s_val = xd.y;
        if (yd.z > 0.5f) s_val = xd.z;
        if (yd.w > 0.5f) s_val = xd.w;
    }

    // tail: 424 float4
    if (tid < TAIL) {
        const int j = SWEEPS * 4 * BLK + tid;
        const float4 y = y4[j];
        const float4 x = x4[j];
        s += e64(x.x); s += e64(x.y); s += e64(x.z); s += e64(x.w);
        if (y.x > 0.5f) s_val = x.x;
        if (y.y > 0.5f) s_val = x.y;
        if (y.z > 0.5f) s_val = x.z;
        if (y.w > 0.5f) s_val = x.w;
    }

    // block reduction of s
    s = wave_reduce_add(s);
    const int wid = tid >> 6;
    if ((tid & 63) == 0) s_wave[wid] = s;
    __syncthreads();

    if (tid == 0) {
        float total = 0.0f;
        #pragma unroll
        for (int w = 0; w < BLK / 64; ++w) total += s_wave[w];

        const float v = s_val;
        // margin1=1, margin2=0.5, margin3=0
        const float THRESH = -0.8775825618903728f;  // cos(pi - 0.5)
        const float theta = cosf(acosf(v) + 0.5f);
        const float tv = (v > THRESH) ? theta : (-2.0f - theta);

        // swap label term: remove exp(64v-64), add exp(64*tv-64)
        total += __expf(64.0f * tv - 64.0f) - __expf(64.0f * v - 64.0f);

        // loss_b = (64 + log(total)) - 64*tv
        row_loss[row] = 64.0f + logf(total) - 64.0f * tv;
    }
}

__global__ __launch_bounds__(BB) void reduce_rows(const float* __restrict__ row_loss,
                                                  float* __restrict__ out) {
    const int tid = threadIdx.x;  // 512 threads
    float v = row_loss[tid];
    v = wave_reduce_add(v);
    __shared__ float s_wave[BB / 64];
    if ((tid & 63) == 0) s_wave[tid >> 6] = v;
    __syncthreads();
    if (tid == 0) {
        float t = 0.0f;
        #pragma unroll
        for (int w = 0; w < BB / 64; ++w) t += s_wave[w];
        out[0] = t * (1.0f / (float)BB);
    }
}

extern "C" void kernel_launch(void* const* d_in, const int* in_sizes, int n_in,
                              void* d_out, int out_size, void* d_ws, size_t ws_size,
                              hipStream_t stream) {
    const float* y_true = (const float*)d_in[0];
    const float* logits = (const float*)d_in[1];
    float* out = (float*)d_out;
    float* row_loss = (float*)d_ws;  // 512 floats

    arcface_rows<<<BB, BLK, 0, stream>>>(y_true, logits, row_loss);
    reduce_rows<<<1, BB, 0, stream>>>(row_loss, out);
}